// Round 11
// baseline (341.393 us; speedup 1.0000x reference)
//
#include <hip/hip_runtime.h>

#define NNODE 50000
#define NEDGE 600000
#define KDIN  239
#define DDIM  128
#define NTILES 3125           // 3125*16 == 50000 exactly
#define NBGEMM 256            // gemm blocks per dispatch
#define HB     128            // histogram / scatter blocks
#define CH     4688           // edges per hist/scat block (128*4688 >= 600000)
#define SWBINS 12500          // bins per sweep (4 sweeps x 12500 = 50000)
#define NSW    4
#define NBSCAN 782            // 64-dst scan tiles (782*64 >= 50000)

typedef _Float16 half8 __attribute__((ext_vector_type(8)));
typedef _Float16 half4 __attribute__((ext_vector_type(4)));
typedef __attribute__((ext_vector_type(4))) float f32x4;

__device__ __forceinline__ ushort f2h(float f){
  union { _Float16 h; ushort u; } c; c.h = (_Float16)f; return c.u;
}
// monotone float<->uint encoding for atomicMax on signed floats
__device__ __forceinline__ unsigned fenc(float f){
  union { float f; unsigned u; } v; v.f = f;
  return (v.u & 0x80000000u) ? ~v.u : (v.u | 0x80000000u);
}
__device__ __forceinline__ float fdec(unsigned k){
  union { unsigned u; float f; } v;
  v.u = (k & 0x80000000u) ? (k & 0x7FFFFFFFu) : ~k;
  return v.f;
}

// ---- prologue: LDS histogram || x->f16 || weight transposes || zero gm ----
__global__ __launch_bounds__(256) void pre_k(const float* __restrict__ x,
    const float* __restrict__ W_in, const float* __restrict__ W_gat, const float* __restrict__ W_h,
    ushort* __restrict__ xf, ushort* __restrict__ BfA, ushort* __restrict__ BfB,
    ushort* __restrict__ BfC, const int* __restrict__ ei, int* __restrict__ partial,
    unsigned* __restrict__ gm)
{
  __shared__ int hbin[SWBINS];                     // 50 KB
  const int b = blockIdx.x, t = threadIdx.x;
  if (b < HB){                                     // per-block LDS histogram of dst
    const int e0 = b*CH, e1 = min(NEDGE, e0+CH);
    for (int s=0; s<NSW; ++s){
      const int lo = s*SWBINS;
      for (int i=t; i<SWBINS; i+=256) hbin[i] = 0;
      __syncthreads();
      for (int e=e0+t; e<e1; e+=256){
        int dst = min(max(ei[NEDGE+e],0), NNODE-1);
        int r = dst - lo;
        if ((unsigned)r < SWBINS) atomicAdd(&hbin[r], 1);   // LDS atomic
      }
      __syncthreads();
      for (int i=t; i<SWBINS; i+=256) partial[b*NNODE + lo + i] = hbin[i];
      __syncthreads();
    }
  } else if (b < HB + 6250){                       // x [N,239] fp32 -> [N,256] f16
    int idx = (b-HB)*256 + t;                      // N*32 threads, 8 elems each
    int r = idx >> 5, c0 = (idx & 31) << 3;
    union { uint4 v; ushort u[8]; } o;
    #pragma unroll
    for (int i=0;i<8;i++){ int c = c0+i; o.u[i] = (c < KDIN) ? f2h(x[(size_t)r*KDIN + c]) : (ushort)0; }
    *(uint4*)(xf + (size_t)r*256 + c0) = o.v;
  } else if (b < HB + 6378){                       // W_in [239,128] -> BfA[n=128][k=256]
    int idx = (b-HB-6250)*256 + t; int n = idx >> 8, k = idx & 255;
    BfA[idx] = (k < KDIN) ? f2h(W_in[(size_t)k*DDIM + n]) : (ushort)0;
  } else if (b < HB + 6442){                       // W_gat -> BfB[n][128]
    int idx = (b-HB-6378)*256 + t; int n = idx >> 7, k = idx & 127;
    BfB[idx] = f2h(W_gat[(size_t)k*DDIM + n]);
  } else if (b < HB + 6506){                       // W_h -> BfC[n][128]
    int idx = (b-HB-6442)*256 + t; int n = idx >> 7, k = idx & 127;
    BfC[idx] = f2h(W_h[(size_t)k*DDIM + n]);
  } else {
    if (t < 3) gm[t] = 0;                          // [gmax_s, gmax_d, gtotal]
  }
}

// ---- MFMA GEMM with LDS-resident B, grid-stride tiles; fused scan/scatter ----
// EPI 0: leaky(.01)(v+bias) -> f16
// EPI 1: v -> f16 + row dots os/od + global max -> gm[0..1]
// EPI 2: h2=leaky(.01)(v+bias); y = h2@W_out + b_out -> outf fp32
// XW 1: blocks >= NBGEMM run the tiled scan (offs/deg/per-histblock bases)
// XW 2: blocks >= NBGEMM run the atomic-free CSR scatter
template<int KSTEPS, int EPI, int XW>
__global__ __launch_bounds__(256, 4) void gemm6_k(
    const ushort* __restrict__ Af, const ushort* __restrict__ Btf,
    const float* __restrict__ bias,
    float* __restrict__ outf, ushort* __restrict__ outh,
    const float* __restrict__ vs, const float* __restrict__ vd,
    float* __restrict__ os, float* __restrict__ od, unsigned* __restrict__ gm,
    const int* __restrict__ ei, int* __restrict__ partial,
    int* __restrict__ offs, int* __restrict__ degv, int* __restrict__ es)
{
  constexpr int KP = KSTEPS*32;
  constexpr int GB2 = 128*KP*2;                    // staged-B bytes
  constexpr int LB = (XW==2 && GB2 < 50048) ? 50048 : GB2;  // union: scat cur / scan T fit
  __shared__ alignas(16) char ldsb[LB];
  if (XW == 1 && blockIdx.x >= NBGEMM){            // tiled scan, 64 dsts/block
    int* T = (int*)ldsb;                           // [128][64] = 32 KB
    const int tt = blockIdx.x - NBGEMM;
    const int d0 = tt*64;
    for (int it=threadIdx.x; it<128*64; it+=256){
      const int bb = it>>6, d = it&63, dd = d0+d;
      T[it] = (dd < NNODE) ? partial[bb*NNODE + dd] : 0;
    }
    __syncthreads();
    if (threadIdx.x < 64){
      const int d = threadIdx.x;
      int deg = 0;
      for (int bb=0;bb<128;++bb) deg += T[bb*64+d];
      int incl = deg;
      #pragma unroll
      for (int off=1; off<64; off<<=1){ int v = __shfl_up(incl,off); if (d>=off) incl += v; }
      const int tot = __shfl(incl, 63);
      int base0 = 0;
      if (d==0) base0 = atomicAdd((int*)(gm+2), tot);  // tile base (any order ok)
      base0 = __shfl(base0, 0);
      const int dd = d0 + d;
      int run = base0 + incl - deg;
      if (dd < NNODE){ offs[dd] = run; degv[dd] = deg; }
      for (int bb=0;bb<128;++bb){                  // per-histblock bases, in place
        if (dd < NNODE) partial[bb*NNODE + dd] = run;
        run += T[bb*64+d];
      }
    }
    return;
  }
  if (XW == 2 && blockIdx.x >= NBGEMM){            // atomic-free CSR scatter
    int* cur = (int*)ldsb;                         // 50 KB cursors
    const int hb = blockIdx.x - NBGEMM;
    const int e0 = hb*CH, e1 = min(NEDGE, e0+CH);
    for (int s=0; s<NSW; ++s){
      const int lo = s*SWBINS;
      for (int i=threadIdx.x; i<SWBINS; i+=256) cur[i] = partial[hb*NNODE + lo + i];
      __syncthreads();
      for (int e=e0+threadIdx.x; e<e1; e+=256){
        int dst = min(max(ei[NEDGE+e],0), NNODE-1);
        int r = dst - lo;
        if ((unsigned)r < SWBINS){
          int src = min(max(ei[e],0), NNODE-1);
          int pos = atomicAdd(&cur[r], 1);         // LDS atomic, no global round trip
          es[pos] = src;                           // fire-and-forget random 4B store
        }
      }
      __syncthreads();
    }
    return;
  }
  // ---- gemm path ----
  ushort* Bsh = (ushort*)ldsb;
  for (int j=threadIdx.x; j < 128*KP/8; j += 256){ // stage B, rotated by n*8 (2-way banks)
    const int flat = j*8;
    const int n = flat / KP;
    const int k = flat - n*KP;
    const int kp = (k + n*8) & (KP-1);
    *(half8*)(Bsh + n*KP + kp) = *(const half8*)(Btf + flat);
  }
  __syncthreads();
  const int lane = threadIdx.x & 63, wave = threadIdx.x >> 6;
  const int q = lane >> 4, c = lane & 15;
  float lmax_s = -3.0e38f, lmax_d = -3.0e38f;
  for (int tile = blockIdx.x*4 + wave; tile < NTILES; tile += NBGEMM*4){
    const int rowBase = tile*16;
    const int arow = rowBase + c;                  // exact: 3125*16 == NNODE
    half8 af[KSTEPS];
    const ushort* __restrict__ ap = Af + (size_t)arow*KP + q*8;
    #pragma unroll
    for (int s=0;s<KSTEPS;s++) af[s] = *(const half8*)(ap + s*32);
    f32x4 acc[8];
    #pragma unroll
    for (int t=0;t<8;t++) acc[t] = (f32x4){0.f,0.f,0.f,0.f};
    #pragma unroll
    for (int s=0;s<KSTEPS;s++){
      #pragma unroll
      for (int t=0;t<8;t++){
        const int n = 16*t + c;
        const int kp = (s*32 + q*8 + n*8) & (KP-1);
        const half8 bf = *(const half8*)(Bsh + n*KP + kp);
        acc[t] = __builtin_amdgcn_mfma_f32_16x16x32_f16(af[s], bf, acc[t], 0,0,0);
      }
    }
    // epilogue: C/D layout col=lane&15, row=(lane>>4)*4+reg  [m89/m91-verified]
    float pr0[4] = {0,0,0,0}, pr1[4] = {0,0,0,0};
    #pragma unroll
    for (int t=0;t<8;t++){
      const int col = 16*t + c;
      const float bv = (EPI != 1) ? bias[col] : 0.f;
      float va=0.f, vb=0.f;
      if (EPI == 1){ va = vs[col]; vb = vd[col]; }
      if (EPI == 2){ va = vs[2*col]; vb = vs[2*col+1]; }
      #pragma unroll
      for (int r=0;r<4;r++){
        const int row = rowBase + q*4 + r;
        float v = acc[t][r] + bv;
        if (EPI != 1) v = (v >= 0.f) ? v : 0.01f*v;
        if (EPI == 0){
          outh[(size_t)row*DDIM + col] = f2h(v);
        } else if (EPI == 1){
          outh[(size_t)row*DDIM + col] = f2h(v);
          pr0[r] += v*va; pr1[r] += v*vb;
        } else {
          pr0[r] += v*va; pr1[r] += v*vb;
        }
      }
    }
    if (EPI >= 1){
      #pragma unroll
      for (int r=0;r<4;r++){
        float s0 = pr0[r], s1 = pr1[r];
        s0 += __shfl_xor(s0,8); s1 += __shfl_xor(s1,8);
        s0 += __shfl_xor(s0,4); s1 += __shfl_xor(s1,4);
        s0 += __shfl_xor(s0,2); s1 += __shfl_xor(s1,2);
        s0 += __shfl_xor(s0,1); s1 += __shfl_xor(s1,1);
        if (EPI == 1){ lmax_s = fmaxf(lmax_s, s0); lmax_d = fmaxf(lmax_d, s1); }
        if (c == 0){
          const int row = rowBase + q*4 + r;
          if (EPI == 1){ os[row] = s0; od[row] = s1; }
          else { float2 y2; y2.x = s0 + vd[0]; y2.y = s1 + vd[1];
                 *(float2*)&outf[(size_t)row*2] = y2; }
        }
      }
    }
  }
  if (EPI == 1){
    #pragma unroll
    for (int off=32; off>0; off>>=1){
      lmax_s = fmaxf(lmax_s, __shfl_xor(lmax_s, off));
      lmax_d = fmaxf(lmax_d, __shfl_xor(lmax_d, off));
    }
    if (lane == 0){ atomicMax(&gm[0], fenc(lmax_s)); atomicMax(&gm[1], fenc(lmax_d)); }
  }
}

// ---- fused softmax+gather: og[dst] = softmax-agg(g f16) + b_gat -> f16 ----
// Each HALF-WAVE owns one dst independently (R8/R10-proven). 4 gather streams.
__global__ __launch_bounds__(256) void agg_k(const ushort* __restrict__ gf,
    const int* __restrict__ offs, const int* __restrict__ degv,
    const int* __restrict__ es,
    const float* __restrict__ a_src, const float* __restrict__ a_dst,
    const unsigned* __restrict__ gm, const float* __restrict__ b_gat,
    ushort* __restrict__ og)
{
  const int lane = threadIdx.x & 63;
  const int half = lane >> 5, li = lane & 31;
  const int dst = blockIdx.x*8 + (threadIdx.x >> 6)*2 + half;
  if (dst >= NNODE) return;
  float M = fdec(gm[0]) + fdec(gm[1]);
  M = (M >= 0.f) ? M : 0.2f*M;
  const int start = offs[dst];
  const int deg = degv[dst];
  const int* __restrict__ bin = es + start;
  const float ad = a_dst[dst];
  f32x4 a0={0,0,0,0}, a1={0,0,0,0}, a2={0,0,0,0}, a3={0,0,0,0};
  float w0s=0.f, w1s=0.f, w2s=0.f, w3s=0.f;
  int j = 0;
  for (; j+3 < deg; j += 4){
    const int i0=bin[j], i1=bin[j+1], i2=bin[j+2], i3=bin[j+3];
    float e0=a_src[i0]+ad; e0=(e0>=0.f)?e0:0.2f*e0;
    float e1=a_src[i1]+ad; e1=(e1>=0.f)?e1:0.2f*e1;
    float e2=a_src[i2]+ad; e2=(e2>=0.f)?e2:0.2f*e2;
    float e3=a_src[i3]+ad; e3=(e3>=0.f)?e3:0.2f*e3;
    const float w0=__expf(e0-M), w1=__expf(e1-M), w2=__expf(e2-M), w3=__expf(e3-M);
    const half4 g0 = *(const half4*)(gf + (size_t)i0*DDIM + li*4);
    const half4 g1 = *(const half4*)(gf + (size_t)i1*DDIM + li*4);
    const half4 g2 = *(const half4*)(gf + (size_t)i2*DDIM + li*4);
    const half4 g3 = *(const half4*)(gf + (size_t)i3*DDIM + li*4);
    #pragma unroll
    for (int i=0;i<4;i++){
      a0[i] += w0*(float)g0[i]; a1[i] += w1*(float)g1[i];
      a2[i] += w2*(float)g2[i]; a3[i] += w3*(float)g3[i];
    }
    w0s += w0; w1s += w1; w2s += w2; w3s += w3;
  }
  for (; j < deg; ++j){
    const int si = bin[j];
    float e0=a_src[si]+ad; e0=(e0>=0.f)?e0:0.2f*e0;
    const float w = __expf(e0-M);
    const half4 gv = *(const half4*)(gf + (size_t)si*DDIM + li*4);
    #pragma unroll
    for (int i=0;i<4;i++) a0[i] += w*(float)gv[i];
    w0s += w;
  }
  {                                                // self-loop (unconditional)
    float evs=a_src[dst]+ad; evs=(evs>=0.f)?evs:0.2f*evs;
    const float w = __expf(evs-M);
    const half4 gv = *(const half4*)(gf + (size_t)dst*DDIM + li*4);
    #pragma unroll
    for (int i=0;i<4;i++) a0[i] += w*(float)gv[i];
    w0s += w;
  }
  const float inv = 1.f/(w0s+w1s+w2s+w3s);         // >= w_self > 0
  const float4 bg = *(const float4*)&b_gat[li*4];
  ushort4 o;
  o.x = f2h((a0[0]+a1[0]+a2[0]+a3[0])*inv + bg.x);
  o.y = f2h((a0[1]+a1[1]+a2[1]+a3[1])*inv + bg.y);
  o.z = f2h((a0[2]+a1[2]+a2[2]+a3[2])*inv + bg.z);
  o.w = f2h((a0[3]+a1[3]+a2[3]+a3[3])*inv + bg.w);
  *(ushort4*)(og + (size_t)dst*DDIM + li*4) = o;
}

extern "C" void kernel_launch(void* const* d_in, const int* in_sizes, int n_in,
                              void* d_out, int out_size, void* d_ws, size_t ws_size,
                              hipStream_t stream)
{
  const float* x       = (const float*)d_in[0];
  const int*   ei      = (const int*)d_in[1];
  // d_in[2] = edge_type (unused by reference)
  const float* W_in    = (const float*)d_in[3];
  const float* b_in    = (const float*)d_in[4];
  const float* W_gat   = (const float*)d_in[5];
  const float* att_src = (const float*)d_in[6];
  const float* att_dst = (const float*)d_in[7];
  const float* b_gat   = (const float*)d_in[8];
  const float* W_h     = (const float*)d_in[9];
  const float* b_h     = (const float*)d_in[10];
  const float* W_out   = (const float*)d_in[11];
  const float* b_out   = (const float*)d_in[12];

  // workspace (~93.2 MB):
  char* ws = (char*)d_ws;
  ushort*   xf      = (ushort*)  (ws + 0);          // x f16 [N,256]    25.6 MB
  ushort*   hf      = (ushort*)  (ws + 25600000);   // h f16 [N,128]    12.8 MB
  ushort*   gf      = (ushort*)  (ws + 38400000);   // g f16 [N,128]    12.8 MB
  ushort*   og      = (ushort*)  (ws + 51200000);   // og f16 [N,128]   12.8 MB
  ushort*   BfA     = (ushort*)  (ws + 64000000);   // 128 KB
  ushort*   BfB     = (ushort*)  (ws + 64200000);   // 32 KB
  ushort*   BfC     = (ushort*)  (ws + 64300000);   // 32 KB
  int*      partial = (int*)     (ws + 64400000);   // [128][50000] = 25.6 MB (then bases)
  int*      es      = (int*)     (ws + 90000000);   // CSR src, 2.4 MB
  int*      offs    = (int*)     (ws + 92400000);   // 200 KB
  int*      degv    = (int*)     (ws + 92600000);   // 200 KB
  float*    a_src   = (float*)   (ws + 92800000);
  float*    a_dst   = (float*)   (ws + 93000000);
  unsigned* gm      = (unsigned*)(ws + 93200000);   // [gmax_s, gmax_d, gtotal]

  // prologue: LDS histogram || x->f16 || weight transposes || zero gm
  pre_k<<<HB + 6506 + 1, 256, 0, stream>>>(x, W_in, W_gat, W_h, xf, BfA, BfB, BfC,
      ei, partial, gm);
  // gemmA: h = leaky(x@W_in + b_in) -> f16   || tiled scan (offs/deg/bases)
  gemm6_k<8,0,1><<<NBGEMM + NBSCAN, 256, 0, stream>>>(xf, BfA, b_in,
      nullptr, hf, nullptr, nullptr, nullptr, nullptr, gm, nullptr, partial, offs, degv, nullptr);
  // gemmB: g = h@W_gat -> f16 + a_src/a_dst + maxes  || atomic-free CSR scatter
  gemm6_k<4,1,2><<<NBGEMM + HB, 256, 0, stream>>>(hf, BfB, nullptr,
      nullptr, gf, att_src, att_dst, a_src, a_dst, gm, ei, partial, nullptr, nullptr, es);
  // fused softmax + gather + normalize
  agg_k<<<6250, 256, 0, stream>>>(gf, offs, degv, es, a_src, a_dst, gm, b_gat, og);
  // gemmC: y = leaky(og@W_h + b_h) @ W_out + b_out -> d_out fp32
  gemm6_k<4,2,0><<<NBGEMM, 256, 0, stream>>>(og, BfC, b_h,
      (float*)d_out, nullptr, W_out, b_out, nullptr, nullptr, nullptr, nullptr, nullptr, nullptr, nullptr, nullptr);
}